// Round 1
// baseline (1507.776 us; speedup 1.0000x reference)
//
#include <hip/hip_runtime.h>

#define NV 50000
#define NE 800000

typedef __bf16 bf16x8 __attribute__((ext_vector_type(8)));
typedef __bf16 bf16x4 __attribute__((ext_vector_type(4)));
typedef float  f32x4  __attribute__((ext_vector_type(4)));

static __device__ __forceinline__ f32x4 mfma16(bf16x8 a, bf16x8 b, f32x4 c) {
  return __builtin_amdgcn_mfma_f32_16x16x32_bf16(a, b, c, 0, 0, 0);
}

// ---- prep: h fp32 -> bf16 (vectorized x4) ----
__global__ void cvt_h_kernel(const float* __restrict__ h, __bf16* __restrict__ hb, int n4) {
  int i = blockIdx.x * blockDim.x + threadIdx.x;
  if (i < n4) {
    f32x4 v = reinterpret_cast<const f32x4*>(h)[i];
    bf16x4 o;
    o[0] = (__bf16)v[0]; o[1] = (__bf16)v[1]; o[2] = (__bf16)v[2]; o[3] = (__bf16)v[3];
    reinterpret_cast<bf16x4*>(hb)[i] = o;
  }
}

// ---- prep: W[K][N] fp32 -> Wt[N][K] bf16 ----
__global__ void transpose_w_kernel(const float* __restrict__ w, __bf16* __restrict__ wt,
                                   int K, int N) {
  int i = blockIdx.x * blockDim.x + threadIdx.x;
  if (i < K * N) {
    int n = i / K, k = i % K;
    wt[i] = (__bf16)w[k * N + n];
  }
}

// Role-swapped MFMA layout:
//   A = Wt (M=out-feat, 16B contiguous frags), B = gathered rows (N=edge/node),
//   C/D: col(lane&15)=edge, row(quad*4+reg)=feat -> lane owns 4 consecutive feats.
// Per wave: 64 edges (4 ntiles) x 128 out feats (8 mtiles). Wave-private LDS
// m-buffer, padded row stride 136 bf16 (272B: 16B-aligned, <=2-way bank conflict).

__global__ __launch_bounds__(128, 2)
void edge_kernel(const __bf16* __restrict__ hb, const int* __restrict__ ei,
                 const __bf16* __restrict__ w1t, const float* __restrict__ b1,
                 const __bf16* __restrict__ w2t, const float* __restrict__ b2,
                 const __bf16* __restrict__ w3t, const float* __restrict__ b3,
                 float* __restrict__ agg)
{
  __shared__ __bf16 lds[2][64 * 136];
  const int lane = threadIdx.x & 63;
  const int wave = threadIdx.x >> 6;
  const int quad = lane >> 4;
  const int l15  = lane & 15;
  const int koff = quad * 8;
  __bf16* mbuf = &lds[wave][0];

  const int ebase = blockIdx.x * 128 + wave * 64;

  int esrc[4], edst[4];
#pragma unroll
  for (int nt = 0; nt < 4; nt++) {
    int e = ebase + nt * 16 + l15;
    esrc[nt] = ei[e];
    edst[nt] = ei[NE + e];
  }

  f32x4 acc[8][4];
#pragma unroll
  for (int mt = 0; mt < 8; mt++)
#pragma unroll
    for (int nt = 0; nt < 4; nt++)
      acc[mt][nt] = (f32x4){0.f, 0.f, 0.f, 0.f};

  // ---------- layer 1: X[64,256] @ W1 -> [64,128] ----------
#pragma unroll
  for (int s = 0; s < 8; s++) {
    const int k = s * 32 + koff;
    bf16x8 B[4];
#pragma unroll
    for (int nt = 0; nt < 4; nt++) {
      const __bf16* p = (s < 4) ? (hb + (long long)esrc[nt] * 128 + k)
                                : (hb + (long long)edst[nt] * 128 + (k - 128));
      B[nt] = *reinterpret_cast<const bf16x8*>(p);
    }
#pragma unroll
    for (int mt = 0; mt < 8; mt++) {
      bf16x8 A = *reinterpret_cast<const bf16x8*>(w1t + (mt * 16 + l15) * 256 + k);
#pragma unroll
      for (int nt = 0; nt < 4; nt++)
        acc[mt][nt] = mfma16(A, B[nt], acc[mt][nt]);
    }
  }

  // epilogue 1: +b1, relu, pack 4 bf16 -> LDS (ds_write_b64)
#pragma unroll
  for (int mt = 0; mt < 8; mt++) {
    f32x4 bias = *reinterpret_cast<const f32x4*>(b1 + mt * 16 + quad * 4);
#pragma unroll
    for (int nt = 0; nt < 4; nt++) {
      bf16x4 o;
#pragma unroll
      for (int r = 0; r < 4; r++) {
        float x = acc[mt][nt][r] + bias[r];
        o[r] = (__bf16)(x > 0.f ? x : 0.f);
      }
      *reinterpret_cast<bf16x4*>(&mbuf[(nt * 16 + l15) * 136 + mt * 16 + quad * 4]) = o;
      acc[mt][nt] = (f32x4){0.f, 0.f, 0.f, 0.f};
    }
  }

  // ---------- layer 2: m1[64,128] @ W2 ----------
#pragma unroll
  for (int s = 0; s < 4; s++) {
    const int k = s * 32 + koff;
    bf16x8 B[4];
#pragma unroll
    for (int nt = 0; nt < 4; nt++)
      B[nt] = *reinterpret_cast<const bf16x8*>(&mbuf[(nt * 16 + l15) * 136 + k]);
#pragma unroll
    for (int mt = 0; mt < 8; mt++) {
      bf16x8 A = *reinterpret_cast<const bf16x8*>(w2t + (mt * 16 + l15) * 128 + k);
#pragma unroll
      for (int nt = 0; nt < 4; nt++)
        acc[mt][nt] = mfma16(A, B[nt], acc[mt][nt]);
    }
  }

  // epilogue 2: +b2, relu -> LDS (reads above precede writes in program order)
#pragma unroll
  for (int mt = 0; mt < 8; mt++) {
    f32x4 bias = *reinterpret_cast<const f32x4*>(b2 + mt * 16 + quad * 4);
#pragma unroll
    for (int nt = 0; nt < 4; nt++) {
      bf16x4 o;
#pragma unroll
      for (int r = 0; r < 4; r++) {
        float x = acc[mt][nt][r] + bias[r];
        o[r] = (__bf16)(x > 0.f ? x : 0.f);
      }
      *reinterpret_cast<bf16x4*>(&mbuf[(nt * 16 + l15) * 136 + mt * 16 + quad * 4]) = o;
      acc[mt][nt] = (f32x4){0.f, 0.f, 0.f, 0.f};
    }
  }

  // ---------- layer 3: m2[64,128] @ W3 -> messages ----------
#pragma unroll
  for (int s = 0; s < 4; s++) {
    const int k = s * 32 + koff;
    bf16x8 B[4];
#pragma unroll
    for (int nt = 0; nt < 4; nt++)
      B[nt] = *reinterpret_cast<const bf16x8*>(&mbuf[(nt * 16 + l15) * 136 + k]);
#pragma unroll
    for (int mt = 0; mt < 8; mt++) {
      bf16x8 A = *reinterpret_cast<const bf16x8*>(w3t + (mt * 16 + l15) * 128 + k);
#pragma unroll
      for (int nt = 0; nt < 4; nt++)
        acc[mt][nt] = mfma16(A, B[nt], acc[mt][nt]);
    }
  }

  // epilogue 3: +b3 (no relu), scatter-add into agg[dst] (fp32 atomics,
  // 4 consecutive addresses per lane)
#pragma unroll
  for (int mt = 0; mt < 8; mt++) {
    f32x4 bias = *reinterpret_cast<const f32x4*>(b3 + mt * 16 + quad * 4);
#pragma unroll
    for (int nt = 0; nt < 4; nt++) {
      float* p = agg + (long long)edst[nt] * 128 + mt * 16 + quad * 4;
#pragma unroll
      for (int r = 0; r < 4; r++)
        unsafeAtomicAdd(p + r, acc[mt][nt][r] + bias[r]);
    }
  }
}

__global__ __launch_bounds__(128, 2)
void node_kernel(const __bf16* __restrict__ hb, const float* __restrict__ agg,
                 const __bf16* __restrict__ wn1t, const float* __restrict__ bn1,
                 const __bf16* __restrict__ wn2t, const float* __restrict__ bn2,
                 float* __restrict__ out)
{
  __shared__ __bf16 lds[2][64 * 136];
  const int lane = threadIdx.x & 63;
  const int wave = threadIdx.x >> 6;
  const int quad = lane >> 4;
  const int l15  = lane & 15;
  const int koff = quad * 8;
  __bf16* mbuf = &lds[wave][0];

  const int nbase = blockIdx.x * 128 + wave * 64;
  int nid[4];
#pragma unroll
  for (int nt = 0; nt < 4; nt++) {
    int n = nbase + nt * 16 + l15;
    nid[nt] = n < NV ? n : 0;
  }

  f32x4 acc[8][4];
#pragma unroll
  for (int mt = 0; mt < 8; mt++)
#pragma unroll
    for (int nt = 0; nt < 4; nt++)
      acc[mt][nt] = (f32x4){0.f, 0.f, 0.f, 0.f};

  // ---------- layer 1: [h, agg][64,256] @ Wn1 ----------
#pragma unroll
  for (int s = 0; s < 8; s++) {
    const int k = s * 32 + koff;
    bf16x8 B[4];
    if (s < 4) {
#pragma unroll
      for (int nt = 0; nt < 4; nt++)
        B[nt] = *reinterpret_cast<const bf16x8*>(hb + (long long)nid[nt] * 128 + k);
    } else {
#pragma unroll
      for (int nt = 0; nt < 4; nt++) {
        const float* ap = agg + (long long)nid[nt] * 128 + (k - 128);
        f32x4 a0 = *reinterpret_cast<const f32x4*>(ap);
        f32x4 a1 = *reinterpret_cast<const f32x4*>(ap + 4);
        bf16x8 bb;
#pragma unroll
        for (int j = 0; j < 4; j++) { bb[j] = (__bf16)a0[j]; bb[4 + j] = (__bf16)a1[j]; }
        B[nt] = bb;
      }
    }
#pragma unroll
    for (int mt = 0; mt < 8; mt++) {
      bf16x8 A = *reinterpret_cast<const bf16x8*>(wn1t + (mt * 16 + l15) * 256 + k);
#pragma unroll
      for (int nt = 0; nt < 4; nt++)
        acc[mt][nt] = mfma16(A, B[nt], acc[mt][nt]);
    }
  }

  // epilogue: +bn1, relu -> LDS
#pragma unroll
  for (int mt = 0; mt < 8; mt++) {
    f32x4 bias = *reinterpret_cast<const f32x4*>(bn1 + mt * 16 + quad * 4);
#pragma unroll
    for (int nt = 0; nt < 4; nt++) {
      bf16x4 o;
#pragma unroll
      for (int r = 0; r < 4; r++) {
        float x = acc[mt][nt][r] + bias[r];
        o[r] = (__bf16)(x > 0.f ? x : 0.f);
      }
      *reinterpret_cast<bf16x4*>(&mbuf[(nt * 16 + l15) * 136 + mt * 16 + quad * 4]) = o;
      acc[mt][nt] = (f32x4){0.f, 0.f, 0.f, 0.f};
    }
  }

  // ---------- layer 2: @ Wn2 ----------
#pragma unroll
  for (int s = 0; s < 4; s++) {
    const int k = s * 32 + koff;
    bf16x8 B[4];
#pragma unroll
    for (int nt = 0; nt < 4; nt++)
      B[nt] = *reinterpret_cast<const bf16x8*>(&mbuf[(nt * 16 + l15) * 136 + k]);
#pragma unroll
    for (int mt = 0; mt < 8; mt++) {
      bf16x8 A = *reinterpret_cast<const bf16x8*>(wn2t + (mt * 16 + l15) * 128 + k);
#pragma unroll
      for (int nt = 0; nt < 4; nt++)
        acc[mt][nt] = mfma16(A, B[nt], acc[mt][nt]);
    }
  }

  // final: +bn2, store fp32 (16B per lane)
#pragma unroll
  for (int mt = 0; mt < 8; mt++) {
    f32x4 bias = *reinterpret_cast<const f32x4*>(bn2 + mt * 16 + quad * 4);
#pragma unroll
    for (int nt = 0; nt < 4; nt++) {
      int n = nbase + nt * 16 + l15;
      if (n < NV) {
        f32x4 v;
#pragma unroll
        for (int r = 0; r < 4; r++) v[r] = acc[mt][nt][r] + bias[r];
        *reinterpret_cast<f32x4*>(out + (long long)n * 128 + mt * 16 + quad * 4) = v;
      }
    }
  }
}

extern "C" void kernel_launch(void* const* d_in, const int* in_sizes, int n_in,
                              void* d_out, int out_size, void* d_ws, size_t ws_size,
                              hipStream_t stream)
{
  const float* h   = (const float*)d_in[0];
  const int*   ei  = (const int*)d_in[1];   // [2][E] int32
  const float* W1  = (const float*)d_in[2];
  const float* b1  = (const float*)d_in[3];
  const float* W2  = (const float*)d_in[4];
  const float* b2  = (const float*)d_in[5];
  const float* W3  = (const float*)d_in[6];
  const float* b3  = (const float*)d_in[7];
  const float* Wn1 = (const float*)d_in[8];
  const float* bn1 = (const float*)d_in[9];
  const float* Wn2 = (const float*)d_in[10];
  const float* bn2 = (const float*)d_in[11];
  float* out = (float*)d_out;

  char* p = (char*)d_ws;
  __bf16* hb   = (__bf16*)p; p += (size_t)NV * 128 * 2;   // 12.8 MB
  __bf16* w1t  = (__bf16*)p; p += 128 * 256 * 2;
  __bf16* w2t  = (__bf16*)p; p += 128 * 128 * 2;
  __bf16* w3t  = (__bf16*)p; p += 128 * 128 * 2;
  __bf16* wn1t = (__bf16*)p; p += 128 * 256 * 2;
  __bf16* wn2t = (__bf16*)p; p += 128 * 128 * 2;
  float*  agg  = (float*)p;  p += (size_t)NV * 128 * 4;   // 25.6 MB

  hipMemsetAsync(agg, 0, (size_t)NV * 128 * 4, stream);

  cvt_h_kernel<<<(NV * 128 / 4 + 255) / 256, 256, 0, stream>>>(h, hb, NV * 128 / 4);
  transpose_w_kernel<<<128, 256, 0, stream>>>(W1,  w1t,  256, 128);
  transpose_w_kernel<<< 64, 256, 0, stream>>>(W2,  w2t,  128, 128);
  transpose_w_kernel<<< 64, 256, 0, stream>>>(W3,  w3t,  128, 128);
  transpose_w_kernel<<<128, 256, 0, stream>>>(Wn1, wn1t, 256, 128);
  transpose_w_kernel<<< 64, 256, 0, stream>>>(Wn2, wn2t, 128, 128);

  edge_kernel<<<NE / 128, 128, 0, stream>>>(hb, ei, w1t, b1, w2t, b2, w3t, b3, agg);
  node_kernel<<<(NV + 127) / 128, 128, 0, stream>>>(hb, agg, wn1t, bn1, wn2t, bn2, out);
}

// Round 2
// 716.312 us; speedup vs baseline: 2.1049x; 2.1049x over previous
//
#include <hip/hip_runtime.h>

#define NV 50000
#define NE 800000

typedef __bf16 bf16x8 __attribute__((ext_vector_type(8)));
typedef __bf16 bf16x4 __attribute__((ext_vector_type(4)));
typedef float  f32x4  __attribute__((ext_vector_type(4)));

static __device__ __forceinline__ f32x4 mfma16(bf16x8 a, bf16x8 b, f32x4 c) {
  return __builtin_amdgcn_mfma_f32_16x16x32_bf16(a, b, c, 0, 0, 0);
}

// ---- prep: h fp32 -> bf16 (vectorized x4) ----
__global__ void cvt_h_kernel(const float* __restrict__ h, __bf16* __restrict__ hb, int n4) {
  int i = blockIdx.x * blockDim.x + threadIdx.x;
  if (i < n4) {
    f32x4 v = reinterpret_cast<const f32x4*>(h)[i];
    bf16x4 o;
    o[0] = (__bf16)v[0]; o[1] = (__bf16)v[1]; o[2] = (__bf16)v[2]; o[3] = (__bf16)v[3];
    reinterpret_cast<bf16x4*>(hb)[i] = o;
  }
}

// ---- prep: W[K][N] fp32 -> Wt[N][K] bf16 ----
__global__ void transpose_w_kernel(const float* __restrict__ w, __bf16* __restrict__ wt,
                                   int K, int N) {
  int i = blockIdx.x * blockDim.x + threadIdx.x;
  if (i < K * N) {
    int n = i / K, k = i % K;
    wt[i] = (__bf16)w[k * N + n];
  }
}

// ---- sort-by-dst machinery ----
__global__ void hist_kernel(const int* __restrict__ ei, int* __restrict__ counts) {
  int e = blockIdx.x * blockDim.x + threadIdx.x;
  if (e < NE) atomicAdd(&counts[ei[NE + e]], 1);
}

// single block, 1024 threads: exclusive scan of counts[NV] -> offsets[NV+1], cursor copy
__global__ __launch_bounds__(1024)
void scan_kernel(const int* __restrict__ counts, int* __restrict__ offsets,
                 int* __restrict__ cursor) {
  __shared__ int part[1024];
  const int t = threadIdx.x;
  const int C = (NV + 1023) / 1024;   // 49
  const int base = t * C;
  int s = 0;
  for (int i = 0; i < C; i++) {
    int idx = base + i;
    if (idx < NV) s += counts[idx];
  }
  part[t] = s;
  __syncthreads();
  for (int off = 1; off < 1024; off <<= 1) {
    int v = 0;
    if (t >= off) v = part[t - off];
    __syncthreads();
    if (t >= off) part[t] += v;
    __syncthreads();
  }
  int run = (t == 0) ? 0 : part[t - 1];
  for (int i = 0; i < C; i++) {
    int idx = base + i;
    if (idx < NV) {
      offsets[idx] = run;
      cursor[idx] = run;
      run += counts[idx];
    }
  }
  if (t == 1023) offsets[NV] = run;   // == NE
}

__global__ void permute_kernel(const int* __restrict__ ei, int* __restrict__ cursor,
                               int* __restrict__ srcs, int* __restrict__ dsts) {
  int e = blockIdx.x * blockDim.x + threadIdx.x;
  if (e < NE) {
    int s = ei[e], d = ei[NE + e];
    int pos = atomicAdd(&cursor[d], 1);
    srcs[pos] = s;
    dsts[pos] = d;
  }
}

// Role-swapped MFMA layout:
//   A = Wt (M=out-feat, 16B contiguous frags), B = gathered rows (N=edge/node),
//   C/D: col(lane&15)=edge, row(quad*4+reg)=feat -> lane owns 4 consecutive feats.
// Per wave: 64 edges (4 ntiles) x 128 out feats (8 mtiles). Wave-private LDS
// m-buffer, padded row stride 136 bf16 (272B: 16B-aligned, <=2-way bank conflict).
// Edges are processed in dst-sorted order; messages stored contiguously to msg[].

__global__ __launch_bounds__(128, 2)
void edge_kernel(const __bf16* __restrict__ hb,
                 const int* __restrict__ srcs, const int* __restrict__ dsts,
                 const __bf16* __restrict__ w1t, const float* __restrict__ b1,
                 const __bf16* __restrict__ w2t, const float* __restrict__ b2,
                 const __bf16* __restrict__ w3t, const float* __restrict__ b3,
                 __bf16* __restrict__ msg)
{
  __shared__ __bf16 lds[2][64 * 136];
  const int lane = threadIdx.x & 63;
  const int wave = threadIdx.x >> 6;
  const int quad = lane >> 4;
  const int l15  = lane & 15;
  const int koff = quad * 8;
  __bf16* mbuf = &lds[wave][0];

  const int ebase = blockIdx.x * 128 + wave * 64;

  int esrc[4], edst[4];
#pragma unroll
  for (int nt = 0; nt < 4; nt++) {
    int e = ebase + nt * 16 + l15;
    esrc[nt] = srcs[e];
    edst[nt] = dsts[e];
  }

  f32x4 acc[8][4];
#pragma unroll
  for (int mt = 0; mt < 8; mt++)
#pragma unroll
    for (int nt = 0; nt < 4; nt++)
      acc[mt][nt] = (f32x4){0.f, 0.f, 0.f, 0.f};

  // ---------- layer 1: X[64,256] @ W1 -> [64,128] ----------
#pragma unroll
  for (int s = 0; s < 8; s++) {
    const int k = s * 32 + koff;
    bf16x8 B[4];
#pragma unroll
    for (int nt = 0; nt < 4; nt++) {
      const __bf16* p = (s < 4) ? (hb + (long long)esrc[nt] * 128 + k)
                                : (hb + (long long)edst[nt] * 128 + (k - 128));
      B[nt] = *reinterpret_cast<const bf16x8*>(p);
    }
#pragma unroll
    for (int mt = 0; mt < 8; mt++) {
      bf16x8 A = *reinterpret_cast<const bf16x8*>(w1t + (mt * 16 + l15) * 256 + k);
#pragma unroll
      for (int nt = 0; nt < 4; nt++)
        acc[mt][nt] = mfma16(A, B[nt], acc[mt][nt]);
    }
  }

  // epilogue 1: +b1, relu, pack 4 bf16 -> LDS (ds_write_b64)
#pragma unroll
  for (int mt = 0; mt < 8; mt++) {
    f32x4 bias = *reinterpret_cast<const f32x4*>(b1 + mt * 16 + quad * 4);
#pragma unroll
    for (int nt = 0; nt < 4; nt++) {
      bf16x4 o;
#pragma unroll
      for (int r = 0; r < 4; r++) {
        float x = acc[mt][nt][r] + bias[r];
        o[r] = (__bf16)(x > 0.f ? x : 0.f);
      }
      *reinterpret_cast<bf16x4*>(&mbuf[(nt * 16 + l15) * 136 + mt * 16 + quad * 4]) = o;
      acc[mt][nt] = (f32x4){0.f, 0.f, 0.f, 0.f};
    }
  }

  // ---------- layer 2: m1[64,128] @ W2 ----------
#pragma unroll
  for (int s = 0; s < 4; s++) {
    const int k = s * 32 + koff;
    bf16x8 B[4];
#pragma unroll
    for (int nt = 0; nt < 4; nt++)
      B[nt] = *reinterpret_cast<const bf16x8*>(&mbuf[(nt * 16 + l15) * 136 + k]);
#pragma unroll
    for (int mt = 0; mt < 8; mt++) {
      bf16x8 A = *reinterpret_cast<const bf16x8*>(w2t + (mt * 16 + l15) * 128 + k);
#pragma unroll
      for (int nt = 0; nt < 4; nt++)
        acc[mt][nt] = mfma16(A, B[nt], acc[mt][nt]);
    }
  }

  // epilogue 2: +b2, relu -> LDS
#pragma unroll
  for (int mt = 0; mt < 8; mt++) {
    f32x4 bias = *reinterpret_cast<const f32x4*>(b2 + mt * 16 + quad * 4);
#pragma unroll
    for (int nt = 0; nt < 4; nt++) {
      bf16x4 o;
#pragma unroll
      for (int r = 0; r < 4; r++) {
        float x = acc[mt][nt][r] + bias[r];
        o[r] = (__bf16)(x > 0.f ? x : 0.f);
      }
      *reinterpret_cast<bf16x4*>(&mbuf[(nt * 16 + l15) * 136 + mt * 16 + quad * 4]) = o;
      acc[mt][nt] = (f32x4){0.f, 0.f, 0.f, 0.f};
    }
  }

  // ---------- layer 3: m2[64,128] @ W3 -> messages ----------
#pragma unroll
  for (int s = 0; s < 4; s++) {
    const int k = s * 32 + koff;
    bf16x8 B[4];
#pragma unroll
    for (int nt = 0; nt < 4; nt++)
      B[nt] = *reinterpret_cast<const bf16x8*>(&mbuf[(nt * 16 + l15) * 136 + k]);
#pragma unroll
    for (int mt = 0; mt < 8; mt++) {
      bf16x8 A = *reinterpret_cast<const bf16x8*>(w3t + (mt * 16 + l15) * 128 + k);
#pragma unroll
      for (int nt = 0; nt < 4; nt++)
        acc[mt][nt] = mfma16(A, B[nt], acc[mt][nt]);
    }
  }

  // epilogue 3: +b3 (no relu), contiguous bf16 row store (sorted position)
#pragma unroll
  for (int mt = 0; mt < 8; mt++) {
    f32x4 bias = *reinterpret_cast<const f32x4*>(b3 + mt * 16 + quad * 4);
#pragma unroll
    for (int nt = 0; nt < 4; nt++) {
      int e = ebase + nt * 16 + l15;
      bf16x4 o;
#pragma unroll
      for (int r = 0; r < 4; r++)
        o[r] = (__bf16)(acc[mt][nt][r] + bias[r]);
      *reinterpret_cast<bf16x4*>(msg + (long long)e * 128 + mt * 16 + quad * 4) = o;
    }
  }
}

// Node kernel: aggregate contiguous msg rows per node into LDS (bf16, B-frag
// layout), then run node MLP with MFMA.
__global__ __launch_bounds__(128)
void node_kernel(const __bf16* __restrict__ hb, const __bf16* __restrict__ msg,
                 const int* __restrict__ offsets,
                 const __bf16* __restrict__ wn1t, const float* __restrict__ bn1,
                 const __bf16* __restrict__ wn2t, const float* __restrict__ bn2,
                 float* __restrict__ out)
{
  __shared__ __bf16 lds[2][64 * 136];
  const int lane = threadIdx.x & 63;
  const int wave = threadIdx.x >> 6;
  const int quad = lane >> 4;
  const int l15  = lane & 15;
  const int koff = quad * 8;
  __bf16* mbuf = &lds[wave][0];

  const int nbase = blockIdx.x * 128 + wave * 64;

  // ---- aggregation: 4 passes, 16 nodes/pass, 4 lanes per node (32 elems each) ----
  const int q4 = lane & 3;
#pragma unroll 1
  for (int pass = 0; pass < 4; pass++) {
    int nl = pass * 16 + (lane >> 2);       // node-local row 0..63
    int n = nbase + nl;
    int start = 0, end = 0;
    if (n < NV) { start = offsets[n]; end = offsets[n + 1]; }
    float accv[32];
#pragma unroll
    for (int j = 0; j < 32; j++) accv[j] = 0.f;
    for (int r = start; r < end; r++) {
      const __bf16* row = msg + (long long)r * 128 + q4 * 32;
#pragma unroll
      for (int c = 0; c < 4; c++) {
        bf16x8 v = *reinterpret_cast<const bf16x8*>(row + c * 8);
#pragma unroll
        for (int j = 0; j < 8; j++) accv[c * 8 + j] += (float)v[j];
      }
    }
#pragma unroll
    for (int c = 0; c < 4; c++) {
      bf16x8 o;
#pragma unroll
      for (int j = 0; j < 8; j++) o[j] = (__bf16)accv[c * 8 + j];
      *reinterpret_cast<bf16x8*>(&mbuf[nl * 136 + q4 * 32 + c * 8]) = o;
    }
  }

  int nid[4];
#pragma unroll
  for (int nt = 0; nt < 4; nt++) {
    int n = nbase + nt * 16 + l15;
    nid[nt] = n < NV ? n : 0;
  }

  f32x4 acc[8][4];
#pragma unroll
  for (int mt = 0; mt < 8; mt++)
#pragma unroll
    for (int nt = 0; nt < 4; nt++)
      acc[mt][nt] = (f32x4){0.f, 0.f, 0.f, 0.f};

  // ---------- layer 1: [h, agg][64,256] @ Wn1 ----------
#pragma unroll
  for (int s = 0; s < 8; s++) {
    const int k = s * 32 + koff;
    bf16x8 B[4];
    if (s < 4) {
#pragma unroll
      for (int nt = 0; nt < 4; nt++)
        B[nt] = *reinterpret_cast<const bf16x8*>(hb + (long long)nid[nt] * 128 + k);
    } else {
#pragma unroll
      for (int nt = 0; nt < 4; nt++)
        B[nt] = *reinterpret_cast<const bf16x8*>(&mbuf[(nt * 16 + l15) * 136 + (k - 128)]);
    }
#pragma unroll
    for (int mt = 0; mt < 8; mt++) {
      bf16x8 A = *reinterpret_cast<const bf16x8*>(wn1t + (mt * 16 + l15) * 256 + k);
#pragma unroll
      for (int nt = 0; nt < 4; nt++)
        acc[mt][nt] = mfma16(A, B[nt], acc[mt][nt]);
    }
  }

  // epilogue: +bn1, relu -> LDS (agg fully consumed above; safe to overwrite)
#pragma unroll
  for (int mt = 0; mt < 8; mt++) {
    f32x4 bias = *reinterpret_cast<const f32x4*>(bn1 + mt * 16 + quad * 4);
#pragma unroll
    for (int nt = 0; nt < 4; nt++) {
      bf16x4 o;
#pragma unroll
      for (int r = 0; r < 4; r++) {
        float x = acc[mt][nt][r] + bias[r];
        o[r] = (__bf16)(x > 0.f ? x : 0.f);
      }
      *reinterpret_cast<bf16x4*>(&mbuf[(nt * 16 + l15) * 136 + mt * 16 + quad * 4]) = o;
      acc[mt][nt] = (f32x4){0.f, 0.f, 0.f, 0.f};
    }
  }

  // ---------- layer 2: @ Wn2 ----------
#pragma unroll
  for (int s = 0; s < 4; s++) {
    const int k = s * 32 + koff;
    bf16x8 B[4];
#pragma unroll
    for (int nt = 0; nt < 4; nt++)
      B[nt] = *reinterpret_cast<const bf16x8*>(&mbuf[(nt * 16 + l15) * 136 + k]);
#pragma unroll
    for (int mt = 0; mt < 8; mt++) {
      bf16x8 A = *reinterpret_cast<const bf16x8*>(wn2t + (mt * 16 + l15) * 128 + k);
#pragma unroll
      for (int nt = 0; nt < 4; nt++)
        acc[mt][nt] = mfma16(A, B[nt], acc[mt][nt]);
    }
  }

  // final: +bn2, store fp32 (16B per lane)
#pragma unroll
  for (int mt = 0; mt < 8; mt++) {
    f32x4 bias = *reinterpret_cast<const f32x4*>(bn2 + mt * 16 + quad * 4);
#pragma unroll
    for (int nt = 0; nt < 4; nt++) {
      int n = nbase + nt * 16 + l15;
      if (n < NV) {
        f32x4 v;
#pragma unroll
        for (int r = 0; r < 4; r++) v[r] = acc[mt][nt][r] + bias[r];
        *reinterpret_cast<f32x4*>(out + (long long)n * 128 + mt * 16 + quad * 4) = v;
      }
    }
  }
}

// ================= fallback path (atomic scatter, round-1 style) =================
__global__ __launch_bounds__(128, 2)
void edge_kernel_atomic(const __bf16* __restrict__ hb, const int* __restrict__ ei,
                        const __bf16* __restrict__ w1t, const float* __restrict__ b1,
                        const __bf16* __restrict__ w2t, const float* __restrict__ b2,
                        const __bf16* __restrict__ w3t, const float* __restrict__ b3,
                        float* __restrict__ agg)
{
  __shared__ __bf16 lds[2][64 * 136];
  const int lane = threadIdx.x & 63;
  const int wave = threadIdx.x >> 6;
  const int quad = lane >> 4;
  const int l15  = lane & 15;
  const int koff = quad * 8;
  __bf16* mbuf = &lds[wave][0];
  const int ebase = blockIdx.x * 128 + wave * 64;

  int esrc[4], edst[4];
#pragma unroll
  for (int nt = 0; nt < 4; nt++) {
    int e = ebase + nt * 16 + l15;
    esrc[nt] = ei[e];
    edst[nt] = ei[NE + e];
  }
  f32x4 acc[8][4];
#pragma unroll
  for (int mt = 0; mt < 8; mt++)
#pragma unroll
    for (int nt = 0; nt < 4; nt++)
      acc[mt][nt] = (f32x4){0.f, 0.f, 0.f, 0.f};
#pragma unroll
  for (int s = 0; s < 8; s++) {
    const int k = s * 32 + koff;
    bf16x8 B[4];
#pragma unroll
    for (int nt = 0; nt < 4; nt++) {
      const __bf16* p = (s < 4) ? (hb + (long long)esrc[nt] * 128 + k)
                                : (hb + (long long)edst[nt] * 128 + (k - 128));
      B[nt] = *reinterpret_cast<const bf16x8*>(p);
    }
#pragma unroll
    for (int mt = 0; mt < 8; mt++) {
      bf16x8 A = *reinterpret_cast<const bf16x8*>(w1t + (mt * 16 + l15) * 256 + k);
#pragma unroll
      for (int nt = 0; nt < 4; nt++)
        acc[mt][nt] = mfma16(A, B[nt], acc[mt][nt]);
    }
  }
#pragma unroll
  for (int mt = 0; mt < 8; mt++) {
    f32x4 bias = *reinterpret_cast<const f32x4*>(b1 + mt * 16 + quad * 4);
#pragma unroll
    for (int nt = 0; nt < 4; nt++) {
      bf16x4 o;
#pragma unroll
      for (int r = 0; r < 4; r++) {
        float x = acc[mt][nt][r] + bias[r];
        o[r] = (__bf16)(x > 0.f ? x : 0.f);
      }
      *reinterpret_cast<bf16x4*>(&mbuf[(nt * 16 + l15) * 136 + mt * 16 + quad * 4]) = o;
      acc[mt][nt] = (f32x4){0.f, 0.f, 0.f, 0.f};
    }
  }
#pragma unroll
  for (int s = 0; s < 4; s++) {
    const int k = s * 32 + koff;
    bf16x8 B[4];
#pragma unroll
    for (int nt = 0; nt < 4; nt++)
      B[nt] = *reinterpret_cast<const bf16x8*>(&mbuf[(nt * 16 + l15) * 136 + k]);
#pragma unroll
    for (int mt = 0; mt < 8; mt++) {
      bf16x8 A = *reinterpret_cast<const bf16x8*>(w2t + (mt * 16 + l15) * 128 + k);
#pragma unroll
      for (int nt = 0; nt < 4; nt++)
        acc[mt][nt] = mfma16(A, B[nt], acc[mt][nt]);
    }
  }
#pragma unroll
  for (int mt = 0; mt < 8; mt++) {
    f32x4 bias = *reinterpret_cast<const f32x4*>(b2 + mt * 16 + quad * 4);
#pragma unroll
    for (int nt = 0; nt < 4; nt++) {
      bf16x4 o;
#pragma unroll
      for (int r = 0; r < 4; r++) {
        float x = acc[mt][nt][r] + bias[r];
        o[r] = (__bf16)(x > 0.f ? x : 0.f);
      }
      *reinterpret_cast<bf16x4*>(&mbuf[(nt * 16 + l15) * 136 + mt * 16 + quad * 4]) = o;
      acc[mt][nt] = (f32x4){0.f, 0.f, 0.f, 0.f};
    }
  }
#pragma unroll
  for (int s = 0; s < 4; s++) {
    const int k = s * 32 + koff;
    bf16x8 B[4];
#pragma unroll
    for (int nt = 0; nt < 4; nt++)
      B[nt] = *reinterpret_cast<const bf16x8*>(&mbuf[(nt * 16 + l15) * 136 + k]);
#pragma unroll
    for (int mt = 0; mt < 8; mt++) {
      bf16x8 A = *reinterpret_cast<const bf16x8*>(w3t + (mt * 16 + l15) * 128 + k);
#pragma unroll
      for (int nt = 0; nt < 4; nt++)
        acc[mt][nt] = mfma16(A, B[nt], acc[mt][nt]);
    }
  }
#pragma unroll
  for (int mt = 0; mt < 8; mt++) {
    f32x4 bias = *reinterpret_cast<const f32x4*>(b3 + mt * 16 + quad * 4);
#pragma unroll
    for (int nt = 0; nt < 4; nt++) {
      float* p = agg + (long long)edst[nt] * 128 + mt * 16 + quad * 4;
#pragma unroll
      for (int r = 0; r < 4; r++)
        unsafeAtomicAdd(p + r, acc[mt][nt][r] + bias[r]);
    }
  }
}

__global__ __launch_bounds__(128, 2)
void node_kernel_agg(const __bf16* __restrict__ hb, const float* __restrict__ agg,
                     const __bf16* __restrict__ wn1t, const float* __restrict__ bn1,
                     const __bf16* __restrict__ wn2t, const float* __restrict__ bn2,
                     float* __restrict__ out)
{
  __shared__ __bf16 lds[2][64 * 136];
  const int lane = threadIdx.x & 63;
  const int wave = threadIdx.x >> 6;
  const int quad = lane >> 4;
  const int l15  = lane & 15;
  const int koff = quad * 8;
  __bf16* mbuf = &lds[wave][0];
  const int nbase = blockIdx.x * 128 + wave * 64;
  int nid[4];
#pragma unroll
  for (int nt = 0; nt < 4; nt++) {
    int n = nbase + nt * 16 + l15;
    nid[nt] = n < NV ? n : 0;
  }
  f32x4 acc[8][4];
#pragma unroll
  for (int mt = 0; mt < 8; mt++)
#pragma unroll
    for (int nt = 0; nt < 4; nt++)
      acc[mt][nt] = (f32x4){0.f, 0.f, 0.f, 0.f};
#pragma unroll
  for (int s = 0; s < 8; s++) {
    const int k = s * 32 + koff;
    bf16x8 B[4];
    if (s < 4) {
#pragma unroll
      for (int nt = 0; nt < 4; nt++)
        B[nt] = *reinterpret_cast<const bf16x8*>(hb + (long long)nid[nt] * 128 + k);
    } else {
#pragma unroll
      for (int nt = 0; nt < 4; nt++) {
        const float* ap = agg + (long long)nid[nt] * 128 + (k - 128);
        f32x4 a0 = *reinterpret_cast<const f32x4*>(ap);
        f32x4 a1 = *reinterpret_cast<const f32x4*>(ap + 4);
        bf16x8 bb;
#pragma unroll
        for (int j = 0; j < 4; j++) { bb[j] = (__bf16)a0[j]; bb[4 + j] = (__bf16)a1[j]; }
        B[nt] = bb;
      }
    }
#pragma unroll
    for (int mt = 0; mt < 8; mt++) {
      bf16x8 A = *reinterpret_cast<const bf16x8*>(wn1t + (mt * 16 + l15) * 256 + k);
#pragma unroll
      for (int nt = 0; nt < 4; nt++)
        acc[mt][nt] = mfma16(A, B[nt], acc[mt][nt]);
    }
  }
#pragma unroll
  for (int mt = 0; mt < 8; mt++) {
    f32x4 bias = *reinterpret_cast<const f32x4*>(bn1 + mt * 16 + quad * 4);
#pragma unroll
    for (int nt = 0; nt < 4; nt++) {
      bf16x4 o;
#pragma unroll
      for (int r = 0; r < 4; r++) {
        float x = acc[mt][nt][r] + bias[r];
        o[r] = (__bf16)(x > 0.f ? x : 0.f);
      }
      *reinterpret_cast<bf16x4*>(&mbuf[(nt * 16 + l15) * 136 + mt * 16 + quad * 4]) = o;
      acc[mt][nt] = (f32x4){0.f, 0.f, 0.f, 0.f};
    }
  }
#pragma unroll
  for (int s = 0; s < 4; s++) {
    const int k = s * 32 + koff;
    bf16x8 B[4];
#pragma unroll
    for (int nt = 0; nt < 4; nt++)
      B[nt] = *reinterpret_cast<const bf16x8*>(&mbuf[(nt * 16 + l15) * 136 + k]);
#pragma unroll
    for (int mt = 0; mt < 8; mt++) {
      bf16x8 A = *reinterpret_cast<const bf16x8*>(wn2t + (mt * 16 + l15) * 128 + k);
#pragma unroll
      for (int nt = 0; nt < 4; nt++)
        acc[mt][nt] = mfma16(A, B[nt], acc[mt][nt]);
    }
  }
#pragma unroll
  for (int mt = 0; mt < 8; mt++) {
    f32x4 bias = *reinterpret_cast<const f32x4*>(bn2 + mt * 16 + quad * 4);
#pragma unroll
    for (int nt = 0; nt < 4; nt++) {
      int n = nbase + nt * 16 + l15;
      if (n < NV) {
        f32x4 v;
#pragma unroll
        for (int r = 0; r < 4; r++) v[r] = acc[mt][nt][r] + bias[r];
        *reinterpret_cast<f32x4*>(out + (long long)n * 128 + mt * 16 + quad * 4) = v;
      }
    }
  }
}

static inline size_t align16(size_t x) { return (x + 15) & ~(size_t)15; }

extern "C" void kernel_launch(void* const* d_in, const int* in_sizes, int n_in,
                              void* d_out, int out_size, void* d_ws, size_t ws_size,
                              hipStream_t stream)
{
  const float* h   = (const float*)d_in[0];
  const int*   ei  = (const int*)d_in[1];   // [2][E] int32
  const float* W1  = (const float*)d_in[2];
  const float* b1  = (const float*)d_in[3];
  const float* W2  = (const float*)d_in[4];
  const float* b2  = (const float*)d_in[5];
  const float* W3  = (const float*)d_in[6];
  const float* b3  = (const float*)d_in[7];
  const float* Wn1 = (const float*)d_in[8];
  const float* bn1 = (const float*)d_in[9];
  const float* Wn2 = (const float*)d_in[10];
  const float* bn2 = (const float*)d_in[11];
  float* out = (float*)d_out;

  // common workspace prefix
  char* p = (char*)d_ws;
  __bf16* hb   = (__bf16*)p; p += align16((size_t)NV * 128 * 2);
  __bf16* w1t  = (__bf16*)p; p += align16(128 * 256 * 2);
  __bf16* w2t  = (__bf16*)p; p += align16(128 * 128 * 2);
  __bf16* w3t  = (__bf16*)p; p += align16(128 * 128 * 2);
  __bf16* wn1t = (__bf16*)p; p += align16(128 * 256 * 2);
  __bf16* wn2t = (__bf16*)p; p += align16(128 * 128 * 2);

  // sorted-path extras
  char* q = p;
  int* counts  = (int*)q; q += align16((size_t)NV * 4);
  int* offsets = (int*)q; q += align16((size_t)(NV + 1) * 4);
  int* cursor  = (int*)q; q += align16((size_t)NV * 4);
  int* srcs    = (int*)q; q += align16((size_t)NE * 4);
  int* dsts    = (int*)q; q += align16((size_t)NE * 4);
  __bf16* msg  = (__bf16*)q; q += align16((size_t)NE * 128 * 2);
  size_t need_sorted = (size_t)(q - (char*)d_ws);

  cvt_h_kernel<<<(NV * 128 / 4 + 255) / 256, 256, 0, stream>>>(h, hb, NV * 128 / 4);
  transpose_w_kernel<<<128, 256, 0, stream>>>(W1,  w1t,  256, 128);
  transpose_w_kernel<<< 64, 256, 0, stream>>>(W2,  w2t,  128, 128);
  transpose_w_kernel<<< 64, 256, 0, stream>>>(W3,  w3t,  128, 128);
  transpose_w_kernel<<<128, 256, 0, stream>>>(Wn1, wn1t, 256, 128);
  transpose_w_kernel<<< 64, 256, 0, stream>>>(Wn2, wn2t, 128, 128);

  if (ws_size >= need_sorted) {
    hipMemsetAsync(counts, 0, (size_t)NV * 4, stream);
    hist_kernel<<<(NE + 255) / 256, 256, 0, stream>>>(ei, counts);
    scan_kernel<<<1, 1024, 0, stream>>>(counts, offsets, cursor);
    permute_kernel<<<(NE + 255) / 256, 256, 0, stream>>>(ei, cursor, srcs, dsts);
    edge_kernel<<<NE / 128, 128, 0, stream>>>(hb, srcs, dsts, w1t, b1, w2t, b2, w3t, b3, msg);
    node_kernel<<<(NV + 127) / 128, 128, 0, stream>>>(hb, msg, offsets, wn1t, bn1, wn2t, bn2, out);
  } else {
    float* agg = (float*)p;   // 25.6 MB
    hipMemsetAsync(agg, 0, (size_t)NV * 128 * 4, stream);
    edge_kernel_atomic<<<NE / 128, 128, 0, stream>>>(hb, ei, w1t, b1, w2t, b2, w3t, b3, agg);
    node_kernel_agg<<<(NV + 127) / 128, 128, 0, stream>>>(hb, agg, wn1t, bn1, wn2t, bn2, out);
  }
}

// Round 4
// 572.760 us; speedup vs baseline: 2.6325x; 1.2506x over previous
//
#include <hip/hip_runtime.h>

#define NV 50000
#define NE 800000
#define XSTR 280   // LDS row stride in bf16: 560B = 16B-aligned, 140 dwords -> uniform bank spread

typedef __bf16 bf16x8 __attribute__((ext_vector_type(8)));
typedef __bf16 bf16x4 __attribute__((ext_vector_type(4)));
typedef float  f32x4  __attribute__((ext_vector_type(4)));

static __device__ __forceinline__ f32x4 mfma16(bf16x8 a, bf16x8 b, f32x4 c) {
  return __builtin_amdgcn_mfma_f32_16x16x32_bf16(a, b, c, 0, 0, 0);
}

// ---- prep: h fp32 -> bf16 ----
__global__ void cvt_h_kernel(const float* __restrict__ h, __bf16* __restrict__ hb, int n4) {
  int i = blockIdx.x * blockDim.x + threadIdx.x;
  if (i < n4) {
    f32x4 v = reinterpret_cast<const f32x4*>(h)[i];
    bf16x4 o;
    o[0] = (__bf16)v[0]; o[1] = (__bf16)v[1]; o[2] = (__bf16)v[2]; o[3] = (__bf16)v[3];
    reinterpret_cast<bf16x4*>(hb)[i] = o;
  }
}

// ---- prep: all 5 weight transposes in one kernel ----
__global__ void prep_w_kernel(const float* __restrict__ W1, const float* __restrict__ W2,
                              const float* __restrict__ W3, const float* __restrict__ Wn1,
                              const float* __restrict__ Wn2,
                              __bf16* __restrict__ w1t, __bf16* __restrict__ w2t,
                              __bf16* __restrict__ w3t, __bf16* __restrict__ wn1t,
                              __bf16* __restrict__ wn2t) {
  int i = blockIdx.x * blockDim.x + threadIdx.x;
  const float* w; __bf16* wt; int K;
  if      (i < 32768)              { w = W1;  wt = w1t;  K = 256; }
  else if (i < 49152)  { i -= 32768; w = W2;  wt = w2t;  K = 128; }
  else if (i < 65536)  { i -= 49152; w = W3;  wt = w3t;  K = 128; }
  else if (i < 98304)  { i -= 65536; w = Wn1; wt = wn1t; K = 256; }
  else if (i < 114688) { i -= 98304; w = Wn2; wt = wn2t; K = 128; }
  else return;
  int n = i / K, k = i % K;
  wt[i] = (__bf16)w[k * 128 + n];
}

// ---- sort-by-dst machinery ----
__global__ void hist_kernel(const int* __restrict__ ei, int* __restrict__ counts) {
  int e = blockIdx.x * blockDim.x + threadIdx.x;
  if (e < NE) atomicAdd(&counts[ei[NE + e]], 1);
}

__global__ __launch_bounds__(1024)
void scan_kernel(const int* __restrict__ counts, int* __restrict__ offsets,
                 int* __restrict__ cursor) {
  __shared__ int part[1024];
  const int t = threadIdx.x;
  const int C = (NV + 1023) / 1024;
  const int base = t * C;
  int s = 0;
  for (int i = 0; i < C; i++) {
    int idx = base + i;
    if (idx < NV) s += counts[idx];
  }
  part[t] = s;
  __syncthreads();
  for (int off = 1; off < 1024; off <<= 1) {
    int v = 0;
    if (t >= off) v = part[t - off];
    __syncthreads();
    if (t >= off) part[t] += v;
    __syncthreads();
  }
  int run = (t == 0) ? 0 : part[t - 1];
  for (int i = 0; i < C; i++) {
    int idx = base + i;
    if (idx < NV) {
      offsets[idx] = run;
      cursor[idx] = run;
      run += counts[idx];
    }
  }
  if (t == 1023) offsets[NV] = run;
}

__global__ void permute_kernel(const int* __restrict__ ei, int* __restrict__ cursor,
                               int* __restrict__ srcs, int* __restrict__ dsts) {
  int e = blockIdx.x * blockDim.x + threadIdx.x;
  if (e < NE) {
    int s = ei[e], d = ei[NE + e];
    int pos = atomicAdd(&cursor[d], 1);
    srcs[pos] = s;
    dsts[pos] = d;
  }
}

// ================= edge kernel: block-cooperative, 64 edges / 4 waves =================
__global__ __launch_bounds__(256, 4)
void edge_kernel(const __bf16* __restrict__ hb,
                 const int* __restrict__ srcs, const int* __restrict__ dsts,
                 const __bf16* __restrict__ w1t, const float* __restrict__ b1,
                 const __bf16* __restrict__ w2t, const float* __restrict__ b2,
                 const __bf16* __restrict__ w3t, const float* __restrict__ b3,
                 __bf16* __restrict__ msg)
{
  __shared__ __bf16 X[64 * XSTR];
  const int t = threadIdx.x;
  const int lane = t & 63;
  const int wave = t >> 6;
  const int quad = lane >> 4;
  const int l15  = lane & 15;
  const int koff = quad * 8;
  const int ebase = blockIdx.x * 64;
  const int mt0 = wave * 2;

  // ---- phase 1: gather (64 rows x 32 chunks = 2048 items) ----
  {
    int idx[8];
#pragma unroll
    for (int it = 0; it < 8; it++) {
      int g = it * 256 + t;
      int row = g >> 5, chunk = g & 31;
      idx[it] = (chunk < 16) ? srcs[ebase + row] : dsts[ebase + row];
    }
    bf16x8 v[8];
#pragma unroll
    for (int it = 0; it < 8; it++) {
      int g = it * 256 + t;
      int chunk = g & 31;
      v[it] = *reinterpret_cast<const bf16x8*>(hb + (long long)idx[it] * 128 + (chunk & 15) * 8);
    }
#pragma unroll
    for (int it = 0; it < 8; it++) {
      int g = it * 256 + t;
      int row = g >> 5, chunk = g & 31;
      *reinterpret_cast<bf16x8*>(&X[row * XSTR + (chunk & 15) * 8 + ((chunk < 16) ? 0 : 128)]) = v[it];
    }
  }
  __syncthreads();

  f32x4 acc[2][4];
#pragma unroll
  for (int j = 0; j < 2; j++)
#pragma unroll
    for (int nt = 0; nt < 4; nt++)
      acc[j][nt] = (f32x4){0.f, 0.f, 0.f, 0.f};

  // ---- layer 1: K=256 ----
#pragma unroll
  for (int s = 0; s < 8; s++) {
    const int k = s * 32 + koff;
    bf16x8 B[4];
#pragma unroll
    for (int nt = 0; nt < 4; nt++)
      B[nt] = *reinterpret_cast<const bf16x8*>(&X[(nt * 16 + l15) * XSTR + k]);
#pragma unroll
    for (int j = 0; j < 2; j++) {
      bf16x8 A = *reinterpret_cast<const bf16x8*>(w1t + ((mt0 + j) * 16 + l15) * 256 + k);
#pragma unroll
      for (int nt = 0; nt < 4; nt++)
        acc[j][nt] = mfma16(A, B[nt], acc[j][nt]);
    }
  }
  __syncthreads();
  // epi 1: +b1, relu -> X[:,0:128]
#pragma unroll
  for (int j = 0; j < 2; j++) {
    f32x4 bias = *reinterpret_cast<const f32x4*>(b1 + (mt0 + j) * 16 + quad * 4);
#pragma unroll
    for (int nt = 0; nt < 4; nt++) {
      bf16x4 o;
#pragma unroll
      for (int r = 0; r < 4; r++) {
        float x = acc[j][nt][r] + bias[r];
        o[r] = (__bf16)(x > 0.f ? x : 0.f);
      }
      *reinterpret_cast<bf16x4*>(&X[(nt * 16 + l15) * XSTR + (mt0 + j) * 16 + quad * 4]) = o;
      acc[j][nt] = (f32x4){0.f, 0.f, 0.f, 0.f};
    }
  }
  __syncthreads();

  // ---- layer 2: K=128 ----
#pragma unroll
  for (int s = 0; s < 4; s++) {
    const int k = s * 32 + koff;
    bf16x8 B[4];
#pragma unroll
    for (int nt = 0; nt < 4; nt++)
      B[nt] = *reinterpret_cast<const bf16x8*>(&X[(nt * 16 + l15) * XSTR + k]);
#pragma unroll
    for (int j = 0; j < 2; j++) {
      bf16x8 A = *reinterpret_cast<const bf16x8*>(w2t + ((mt0 + j) * 16 + l15) * 128 + k);
#pragma unroll
      for (int nt = 0; nt < 4; nt++)
        acc[j][nt] = mfma16(A, B[nt], acc[j][nt]);
    }
  }
  __syncthreads();
  // epi 2: +b2, relu -> X[:,0:128]
#pragma unroll
  for (int j = 0; j < 2; j++) {
    f32x4 bias = *reinterpret_cast<const f32x4*>(b2 + (mt0 + j) * 16 + quad * 4);
#pragma unroll
    for (int nt = 0; nt < 4; nt++) {
      bf16x4 o;
#pragma unroll
      for (int r = 0; r < 4; r++) {
        float x = acc[j][nt][r] + bias[r];
        o[r] = (__bf16)(x > 0.f ? x : 0.f);
      }
      *reinterpret_cast<bf16x4*>(&X[(nt * 16 + l15) * XSTR + (mt0 + j) * 16 + quad * 4]) = o;
      acc[j][nt] = (f32x4){0.f, 0.f, 0.f, 0.f};
    }
  }
  __syncthreads();

  // ---- layer 3: K=128 ----
#pragma unroll
  for (int s = 0; s < 4; s++) {
    const int k = s * 32 + koff;
    bf16x8 B[4];
#pragma unroll
    for (int nt = 0; nt < 4; nt++)
      B[nt] = *reinterpret_cast<const bf16x8*>(&X[(nt * 16 + l15) * XSTR + k]);
#pragma unroll
    for (int j = 0; j < 2; j++) {
      bf16x8 A = *reinterpret_cast<const bf16x8*>(w3t + ((mt0 + j) * 16 + l15) * 128 + k);
#pragma unroll
      for (int nt = 0; nt < 4; nt++)
        acc[j][nt] = mfma16(A, B[nt], acc[j][nt]);
    }
  }
  __syncthreads();
  // epi 3: +b3 (no relu) -> X[:,0:128]
#pragma unroll
  for (int j = 0; j < 2; j++) {
    f32x4 bias = *reinterpret_cast<const f32x4*>(b3 + (mt0 + j) * 16 + quad * 4);
#pragma unroll
    for (int nt = 0; nt < 4; nt++) {
      bf16x4 o;
#pragma unroll
      for (int r = 0; r < 4; r++)
        o[r] = (__bf16)(acc[j][nt][r] + bias[r]);
      *reinterpret_cast<bf16x4*>(&X[(nt * 16 + l15) * XSTR + (mt0 + j) * 16 + quad * 4]) = o;
    }
  }
  __syncthreads();

  // ---- phase 3: coalesced msg store (64 rows x 16 chunks = 1024 items) ----
  // BUGFIX r3->r4: was it<8 (2048 items -> rows 64..127 OOB, clobbered the
  // NEXT block's msg rows). 64*16/256 = 4 iterations exactly.
#pragma unroll
  for (int it = 0; it < 4; it++) {
    int g = it * 256 + t;
    int row = g >> 4, c = (g & 15) * 8;
    bf16x8 vv = *reinterpret_cast<const bf16x8*>(&X[row * XSTR + c]);
    *reinterpret_cast<bf16x8*>(msg + (long long)(ebase + row) * 128 + c) = vv;
  }
}

// ================= node kernel: block-cooperative, 64 nodes / 4 waves =================
__global__ __launch_bounds__(256, 4)
void node_kernel(const __bf16* __restrict__ hb, const __bf16* __restrict__ msg,
                 const int* __restrict__ offsets,
                 const __bf16* __restrict__ wn1t, const float* __restrict__ bn1,
                 const __bf16* __restrict__ wn2t, const float* __restrict__ bn2,
                 float* __restrict__ out)
{
  __shared__ __bf16 X[64 * XSTR];
  const int t = threadIdx.x;
  const int lane = t & 63;
  const int wave = t >> 6;
  const int quad = lane >> 4;
  const int l15  = lane & 15;
  const int koff = quad * 8;
  const int nbase = blockIdx.x * 64;
  const int mt0 = wave * 2;

  // ---- gather h rows -> X[:,0:128] (64 rows x 16 chunks = 1024 items) ----
#pragma unroll
  for (int it = 0; it < 4; it++) {
    int g = it * 256 + t;
    int row = g >> 4, c = (g & 15) * 8;
    int n = nbase + row;
    int node = n < NV ? n : 0;
    bf16x8 v = *reinterpret_cast<const bf16x8*>(hb + (long long)node * 128 + c);
    *reinterpret_cast<bf16x8*>(&X[row * XSTR + c]) = v;
  }

  // ---- aggregate msg rows -> X[:,128:256]; 4 threads per node ----
  {
    const int nl = t >> 2;        // 0..63
    const int q4 = t & 3;
    const int n = nbase + nl;
    int start = 0, end = 0;
    if (n < NV) { start = offsets[n]; end = offsets[n + 1]; }
    float accv[32];
#pragma unroll
    for (int j = 0; j < 32; j++) accv[j] = 0.f;
    for (int r = start; r < end; r++) {
      const __bf16* row = msg + (long long)r * 128 + q4 * 32;
#pragma unroll
      for (int c = 0; c < 4; c++) {
        bf16x8 v = *reinterpret_cast<const bf16x8*>(row + c * 8);
#pragma unroll
        for (int j = 0; j < 8; j++) accv[c * 8 + j] += (float)v[j];
      }
    }
#pragma unroll
    for (int c = 0; c < 4; c++) {
      bf16x8 o;
#pragma unroll
      for (int j = 0; j < 8; j++) o[j] = (__bf16)accv[c * 8 + j];
      *reinterpret_cast<bf16x8*>(&X[nl * XSTR + 128 + q4 * 32 + c * 8]) = o;
    }
  }
  __syncthreads();

  f32x4 acc[2][4];
#pragma unroll
  for (int j = 0; j < 2; j++)
#pragma unroll
    for (int nt = 0; nt < 4; nt++)
      acc[j][nt] = (f32x4){0.f, 0.f, 0.f, 0.f};

  // ---- layer 1: K=256 ([h, agg] @ Wn1) ----
#pragma unroll
  for (int s = 0; s < 8; s++) {
    const int k = s * 32 + koff;
    bf16x8 B[4];
#pragma unroll
    for (int nt = 0; nt < 4; nt++)
      B[nt] = *reinterpret_cast<const bf16x8*>(&X[(nt * 16 + l15) * XSTR + k]);
#pragma unroll
    for (int j = 0; j < 2; j++) {
      bf16x8 A = *reinterpret_cast<const bf16x8*>(wn1t + ((mt0 + j) * 16 + l15) * 256 + k);
#pragma unroll
      for (int nt = 0; nt < 4; nt++)
        acc[j][nt] = mfma16(A, B[nt], acc[j][nt]);
    }
  }
  __syncthreads();
  // epi: +bn1, relu -> X[:,0:128]
#pragma unroll
  for (int j = 0; j < 2; j++) {
    f32x4 bias = *reinterpret_cast<const f32x4*>(bn1 + (mt0 + j) * 16 + quad * 4);
#pragma unroll
    for (int nt = 0; nt < 4; nt++) {
      bf16x4 o;
#pragma unroll
      for (int r = 0; r < 4; r++) {
        float x = acc[j][nt][r] + bias[r];
        o[r] = (__bf16)(x > 0.f ? x : 0.f);
      }
      *reinterpret_cast<bf16x4*>(&X[(nt * 16 + l15) * XSTR + (mt0 + j) * 16 + quad * 4]) = o;
      acc[j][nt] = (f32x4){0.f, 0.f, 0.f, 0.f};
    }
  }
  __syncthreads();

  // ---- layer 2: K=128 ----
#pragma unroll
  for (int s = 0; s < 4; s++) {
    const int k = s * 32 + koff;
    bf16x8 B[4];
#pragma unroll
    for (int nt = 0; nt < 4; nt++)
      B[nt] = *reinterpret_cast<const bf16x8*>(&X[(nt * 16 + l15) * XSTR + k]);
#pragma unroll
    for (int j = 0; j < 2; j++) {
      bf16x8 A = *reinterpret_cast<const bf16x8*>(wn2t + ((mt0 + j) * 16 + l15) * 128 + k);
#pragma unroll
      for (int nt = 0; nt < 4; nt++)
        acc[j][nt] = mfma16(A, B[nt], acc[j][nt]);
    }
  }
  __syncthreads();
  // epi: +bn2 -> fp32 staging in X (rows of 140 f32)
  {
    float* OF = reinterpret_cast<float*>(&X[0]);
#pragma unroll
    for (int j = 0; j < 2; j++) {
      f32x4 bias = *reinterpret_cast<const f32x4*>(bn2 + (mt0 + j) * 16 + quad * 4);
#pragma unroll
      for (int nt = 0; nt < 4; nt++) {
        f32x4 v;
#pragma unroll
        for (int r = 0; r < 4; r++) v[r] = acc[j][nt][r] + bias[r];
        *reinterpret_cast<f32x4*>(&OF[(nt * 16 + l15) * 140 + (mt0 + j) * 16 + quad * 4]) = v;
      }
    }
  }
  __syncthreads();

  // ---- coalesced out store (64 rows x 32 f32x4-chunks = 2048 items) ----
  {
    const float* OF = reinterpret_cast<const float*>(&X[0]);
#pragma unroll
    for (int it = 0; it < 8; it++) {
      int g = it * 256 + t;
      int row = g >> 5, c = (g & 31) * 4;
      int n = nbase + row;
      if (n < NV) {
        f32x4 v = *reinterpret_cast<const f32x4*>(&OF[row * 140 + c]);
        *reinterpret_cast<f32x4*>(out + (long long)n * 128 + c) = v;
      }
    }
  }
}

static inline size_t align16(size_t x) { return (x + 15) & ~(size_t)15; }

extern "C" void kernel_launch(void* const* d_in, const int* in_sizes, int n_in,
                              void* d_out, int out_size, void* d_ws, size_t ws_size,
                              hipStream_t stream)
{
  const float* h   = (const float*)d_in[0];
  const int*   ei  = (const int*)d_in[1];
  const float* W1  = (const float*)d_in[2];
  const float* b1  = (const float*)d_in[3];
  const float* W2  = (const float*)d_in[4];
  const float* b2  = (const float*)d_in[5];
  const float* W3  = (const float*)d_in[6];
  const float* b3  = (const float*)d_in[7];
  const float* Wn1 = (const float*)d_in[8];
  const float* bn1 = (const float*)d_in[9];
  const float* Wn2 = (const float*)d_in[10];
  const float* bn2 = (const float*)d_in[11];
  float* out = (float*)d_out;

  char* p = (char*)d_ws;
  __bf16* hb   = (__bf16*)p; p += align16((size_t)NV * 128 * 2);
  __bf16* w1t  = (__bf16*)p; p += align16(128 * 256 * 2);
  __bf16* w2t  = (__bf16*)p; p += align16(128 * 128 * 2);
  __bf16* w3t  = (__bf16*)p; p += align16(128 * 128 * 2);
  __bf16* wn1t = (__bf16*)p; p += align16(128 * 256 * 2);
  __bf16* wn2t = (__bf16*)p; p += align16(128 * 128 * 2);
  int* counts  = (int*)p; p += align16((size_t)NV * 4);
  int* offsets = (int*)p; p += align16((size_t)(NV + 1) * 4);
  int* cursor  = (int*)p; p += align16((size_t)NV * 4);
  int* srcs    = (int*)p; p += align16((size_t)NE * 4);
  int* dsts    = (int*)p; p += align16((size_t)NE * 4);
  __bf16* msg  = (__bf16*)p; p += align16((size_t)NE * 128 * 2);

  hipMemsetAsync(counts, 0, (size_t)NV * 4, stream);
  cvt_h_kernel<<<(NV * 128 / 4 + 255) / 256, 256, 0, stream>>>(h, hb, NV * 128 / 4);
  prep_w_kernel<<<(114688 + 255) / 256, 256, 0, stream>>>(W1, W2, W3, Wn1, Wn2,
                                                          w1t, w2t, w3t, wn1t, wn2t);
  hist_kernel<<<(NE + 255) / 256, 256, 0, stream>>>(ei, counts);
  scan_kernel<<<1, 1024, 0, stream>>>(counts, offsets, cursor);
  permute_kernel<<<(NE + 255) / 256, 256, 0, stream>>>(ei, cursor, srcs, dsts);
  edge_kernel<<<NE / 64, 256, 0, stream>>>(hb, srcs, dsts, w1t, b1, w2t, b2, w3t, b3, msg);
  node_kernel<<<(NV + 63) / 64, 256, 0, stream>>>(hb, msg, offsets, wn1t, bn1, wn2t, bn2, out);
}